// Round 4
// baseline (1283.614 us; speedup 1.0000x reference)
//
#include <hip/hip_runtime.h>

#define TT 512
#define HH 1024
#define NC 8192     // 2 dirs * 4 gates * 1024 units
#define TAGBASE 0x40000000u  // tag floats ~2.0; never aliases h/poison data

// ---- ws layout (float units) ----
// [0, 4194304)            Gx[512][8192]
// [4194304, ...)          xch[512][2][1024] uint64 tagged h-exchange slots
#define WS_GX    0
#define WS_X     4194304

__device__ __forceinline__ float rdlane(float v, int l) {
  return __int_as_float(__builtin_amdgcn_readlane(__float_as_int(v), l));
}
__device__ __forceinline__ float fsig(float x) {
  float e = __builtin_amdgcn_exp2f(-1.44269504f * x);
  return __builtin_amdgcn_rcpf(1.f + e);
}
__device__ __forceinline__ float ftanh(float x) {
  float e = __builtin_amdgcn_exp2f(2.88539009f * x);
  return fmaf(-2.f, __builtin_amdgcn_rcpf(1.f + e), 1.f);
}

// ---------------- Phase 1: fused embed + input projection GEMM ----------------
// Gx[t][c] = sum_k (E[tok[t]][k]+be[k]) * W_d[g][k][u] + b_d[g][u]
// line layout: c = d*4096 + bp*64 + g*16 + ur   (gate-major within 64-lane line)
// tile 128t x 64c, 256 threads, acc[8][4]; grid = (128 c-tiles, 4 t-tiles)
__global__ __launch_bounds__(256) void k_gemm(const int* __restrict__ tok,
                                              const float* __restrict__ E,
                                              const float* __restrict__ be,
                                              const float* __restrict__ Wr,
                                              const float* __restrict__ Wl,
                                              const float* __restrict__ br,
                                              const float* __restrict__ bl,
                                              float* __restrict__ Gx) {
  __shared__ float As[32][132];  // [k][t]
  __shared__ float Bs[32][68];   // [k][c]
  __shared__ int tokL[128];
  int ct = blockIdx.x, ttile = blockIdx.y;
  int tid = threadIdx.x;
  int d = ct >> 6;
  int bp = ct & 63;
  int u0 = bp << 4;
  const float* W = d ? Wl : Wr;
  const float* bias = d ? bl : br;
  int t0 = ttile * 128;
  int tc = tid & 15, tr = tid >> 4;

  if (tid < 128) tokL[tid] = tok[t0 + tid];

  float acc[8][4];
#pragma unroll
  for (int i = 0; i < 8; ++i)
#pragma unroll
    for (int j = 0; j < 4; ++j) acc[i][j] = 0.f;

  // A staging decode: q = pass*256+tid -> tl = q>>3 (0..127), k = 4*(q&7)
  int a_tl = tid >> 3, a_kq = (tid & 7) << 2;
  // B staging decode: q = pass*256+tid -> k = q>>4, c0 = (q&15)*4
  int b_k = tid >> 4, b_c0 = (tid & 15) << 2;
  int b_g = b_c0 >> 4;
  int b_u = u0 + (b_c0 & 15);

  for (int k0 = 0; k0 < HH; k0 += 32) {
    __syncthreads();
    // ---- A: 128t x 32k from E rows (+be), float4 along k ----
#pragma unroll
    for (int p = 0; p < 4; ++p) {
      int tl = a_tl + (p << 5);
      int row = tokL[tl];
      float4 ev = *(const float4*)&E[(size_t)row * HH + k0 + a_kq];
      float4 bv4 = *(const float4*)&be[k0 + a_kq];
      As[a_kq + 0][tl] = ev.x + bv4.x;
      As[a_kq + 1][tl] = ev.y + bv4.y;
      As[a_kq + 2][tl] = ev.z + bv4.z;
      As[a_kq + 3][tl] = ev.w + bv4.w;
    }
    // ---- B: 32k x 64c from W, float4 along u ----
#pragma unroll
    for (int p = 0; p < 2; ++p) {
      int k = b_k + (p << 4);
      float4 wv = *(const float4*)&W[((size_t)b_g * 2048 + k0 + k) * HH + b_u];
      *(float4*)&Bs[k][b_c0] = wv;
    }
    __syncthreads();
#pragma unroll
    for (int k = 0; k < 32; ++k) {
      float4 bv = *(const float4*)&Bs[k][tc << 2];
      float4 a0 = *(const float4*)&As[k][tr << 3];
      float4 a1 = *(const float4*)&As[k][(tr << 3) + 4];
      float av[8] = {a0.x, a0.y, a0.z, a0.w, a1.x, a1.y, a1.z, a1.w};
#pragma unroll
      for (int i = 0; i < 8; ++i) {
        acc[i][0] = fmaf(av[i], bv.x, acc[i][0]);
        acc[i][1] = fmaf(av[i], bv.y, acc[i][1]);
        acc[i][2] = fmaf(av[i], bv.z, acc[i][2]);
        acc[i][3] = fmaf(av[i], bv.w, acc[i][3]);
      }
    }
  }
  // epilogue: bias (per gate/unit) + store; c = g*16+u order
  int cg = tc >> 2;                  // gate of this thread's 4 cols
  int cu = u0 + ((tc & 3) << 2);     // first unit of the 4 cols
  float b0 = bias[cg * HH + cu + 0];
  float b1 = bias[cg * HH + cu + 1];
  float b2 = bias[cg * HH + cu + 2];
  float b3 = bias[cg * HH + cu + 3];
  size_t cbase = (size_t)(d << 12) + (bp << 6) + (tc << 2);
#pragma unroll
  for (int i = 0; i < 8; ++i) {
    int t = t0 + (tr << 3) + i;
    float4 o;
    o.x = acc[i][0] + b0;
    o.y = acc[i][1] + b1;
    o.z = acc[i][2] + b2;
    o.w = acc[i][3] + b3;
    *(float4*)&Gx[(size_t)t * NC + cbase] = o;
  }
}

// ---------------- Phase 2: persistent bidirectional LSTM scan ----------------
// 128 blocks (64 fwd, 64 bwd) x 1024 threads (16 waves). Block owns 16 hidden
// units; line layout c = g*16 + ur (g = l>>4, ur = l&15). Wave w consumes
// h-slice [64w, 64w+64). Recurrent weights in registers. h exchange:
// write-once tagged 8B words {tag|float}, relaxed agent atomics, no fences.
__global__ __launch_bounds__(1024, 1) void k_scan(const float* __restrict__ Wr,
                                                  const float* __restrict__ Wl,
                                                  const float* __restrict__ Gx,
                                                  unsigned long long* __restrict__ xch,
                                                  float* __restrict__ out) {
  int b = blockIdx.x;
  int d = b >> 6, bp = b & 63;
  int tid = threadIdx.x;
  int w = tid >> 6, l = tid & 63;
  int u0 = bp << 4;
  int g = l >> 4, ur = l & 15;
  const float* W = d ? Wl : Wr;

  // one-time register load of recurrent weights: W_d[g][1024 + 64w + j][u0+ur]
  float wreg[64];
  {
    const float* wb = W + ((size_t)g * 2048 + HH + (w << 6)) * HH + (u0 + ur);
#pragma unroll
    for (int j = 0; j < 64; ++j) wreg[j] = wb[(size_t)j * HH];
  }

  __shared__ float red[2][16][64];
  float c_reg = 0.f;
  const float* gxbase = Gx + (d << 12) + (bp << 6);
  unsigned long long* xd = xch + ((size_t)d << 10);

  for (int t = 0; t < TT; ++t) {
    int p = t & 1;
    // independent of h: issue Gx load early (completes during poll)
    float s_gx = 0.f;
    if (w == 0) {
      int rt = d ? (TT - 1 - t) : t;  // backward consumes reversed sequence
      s_gx = gxbase[(size_t)rt * NC + l];
    }

    float partial = 0.f;
    if (t > 0) {
      unsigned long long* slot = xd + (((size_t)(t - 1)) << 11) + (w << 6) + l;
      unsigned int want = TAGBASE + (unsigned int)t;
      unsigned long long v;
      while (true) {
        v = __hip_atomic_load(slot, __ATOMIC_RELAXED, __HIP_MEMORY_SCOPE_AGENT);
        if (__all((unsigned int)(v >> 32) == want)) break;
        __builtin_amdgcn_s_sleep(1);
      }
      float hv = __int_as_float((int)(unsigned int)v);  // h[64w + l]
      float acc0 = 0.f, acc1 = 0.f;
#pragma unroll
      for (int j = 0; j < 64; j += 2) {
        acc0 = fmaf(rdlane(hv, j), wreg[j], acc0);
        acc1 = fmaf(rdlane(hv, j + 1), wreg[j + 1], acc1);
      }
      partial = acc0 + acc1;
    }
    red[p][w][l] = partial;
    __syncthreads();  // single barrier/step (red is double-buffered)

    if (w == 0) {
      float sval = s_gx;
#pragma unroll
      for (int ww = 0; ww < 16; ++ww) sval += red[p][ww][l];
      // gates for unit (l&15) live at lanes {u, 16+u, 32+u, 48+u}
      int uu4 = l & 15;
      float gi = __shfl(sval, uu4);
      float go = __shfl(sval, 16 + uu4);
      float gf = __shfl(sval, 32 + uu4);
      float gc = __shfl(sval, 48 + uu4);
      float ig = fsig(gi);
      float og = fsig(go);
      float fg = fsig(gf);
      float cg2 = ftanh(gc);
      c_reg = fg * c_reg + ig * cg2;
      float hval = og * ftanh(c_reg);

      if (l < 16) {
        int uu = u0 + l;
        // publish h_{t+1}: single 8B tagged store, fire-and-forget
        unsigned long long val =
            (((unsigned long long)(TAGBASE + (unsigned int)(t + 1))) << 32) |
            (unsigned int)__float_as_int(hval);
        __hip_atomic_store(xd + (((size_t)t) << 11) + uu, val, __ATOMIC_RELAXED,
                           __HIP_MEMORY_SCOPE_AGENT);
        // fire-and-forget outputs (off the critical chain)
        out[(size_t)t * 2048 + (d << 10) + uu] = hval;  // annotations
        if (d == 0 && t == TT - 1) {
          out[(size_t)TT * 2048 + uu] = hval;        // h_f
          out[(size_t)TT * 2048 + HH + uu] = c_reg;  // c_f
        }
      }
    }
  }
}

extern "C" void kernel_launch(void* const* d_in, const int* in_sizes, int n_in,
                              void* d_out, int out_size, void* d_ws, size_t ws_size,
                              hipStream_t stream) {
  const int* tok = (const int*)d_in[0];
  const float* E = (const float*)d_in[1];
  const float* be = (const float*)d_in[2];
  const float* Wr = (const float*)d_in[3];
  const float* br = (const float*)d_in[4];
  const float* Wl = (const float*)d_in[5];
  const float* bl = (const float*)d_in[6];
  float* out = (float*)d_out;
  float* ws = (float*)d_ws;

  float* Gx = ws + WS_GX;
  unsigned long long* xch = (unsigned long long*)(ws + WS_X);

  // No memset: exchange slots are write-once; tag TAGBASE+t can't alias
  // 0xAA poison or any float data ever stored there.

  k_gemm<<<dim3(128, 4), dim3(256), 0, stream>>>(tok, E, be, Wr, Wl, br, bl, Gx);
  k_scan<<<dim3(128), dim3(1024), 0, stream>>>(Wr, Wl, Gx, xch, out);
}